// Round 19
// baseline (546.755 us; speedup 1.0000x reference)
//
#include <hip/hip_runtime.h>
#include <math.h>

#define NN   100000
#define NE   1000000
#define CIN  128
#define COUT 64
#define BN_EPS 1e-5f
#define NB    391      // ceil(NN/256) level-1 buckets (dst>>8)
#define NBLK1 128      // blocks per branch in sort phases 1/3
#define CHUNK_E ((NE + NBLK1 - 1) / NBLK1)   // 7813
#define MT    64       // mlp2 nodes per wave-group
#define MG    ((NN + MT - 1) / MT)           // 1563 groups per branch

// ---- workspace layout (4-byte element offsets) ----
#define Y1B_OFF    0                        // 9,600,000 uints (3 branches)
#define COL_OFF    9600000                  // 3*NE ints
#define ROWPTR_OFF 12600000                 // 3*(NN+1) ints
#define OFF_OFF    12900016                 // 3*NB*NBLK1 ints (150144)
#define W1P_OFF    13050160                 // 3*CIN*COUT floats
#define C1_OFF     (W1P_OFF + 3*CIN*COUT)
#define INSUM_OFF  (C1_OFF + 3*COUT)
#define INSQ_OFF   (INSUM_OFF + CIN)
#define OSUM_OFF   (INSQ_OFF + CIN)
#define OSQ_OFF    (OSUM_OFF + 3*COUT)
#define SCALE_OFF  (OSQ_OFF + 3*COUT)
#define SHIFT_OFF  (SCALE_OFF + CIN)
#define OBNS_OFF   (SHIFT_OFF + CIN)
#define OBNB_OFF   (OBNS_OFF + 3*COUT)
#define ZERO_OFF   INSUM_OFF
#define ZERO_CNT   (2*CIN + 6*COUT)         // 640 floats

__device__ __forceinline__ unsigned bf16_rne(float f) {
    unsigned u = __float_as_uint(f);
    return (u + 0x7FFFu + ((u >> 16) & 1u)) >> 16;
}
__device__ __forceinline__ float lo16f(unsigned u) { return __uint_as_float(u << 16); }
__device__ __forceinline__ float hi16f(unsigned u) { return __uint_as_float(u & 0xFFFF0000u); }

// ---- input BN: per-channel sum/sumsq over nodes ----
__global__ __launch_bounds__(256) void k_in_stats(const float* __restrict__ x,
                                                  float* __restrict__ ws) {
    int tid = blockIdx.x * blockDim.x + threadIdx.x;
    int c = tid & (CIN - 1);
    int r0 = tid >> 7;
    int rstride = (gridDim.x * blockDim.x) >> 7;
    float s = 0.f, ss = 0.f;
    for (int r = r0; r < NN; r += rstride) {
        float v = x[(size_t)r * CIN + c];
        s += v; ss += v * v;
    }
    unsafeAtomicAdd(&ws[INSUM_OFF + c], s);
    unsafeAtomicAdd(&ws[INSQ_OFF + c], ss);
}

__global__ void k_in_finalize(const float* __restrict__ g, const float* __restrict__ b,
                              float* __restrict__ ws) {
    int c = threadIdx.x;   // 128 threads
    float mu  = ws[INSUM_OFF + c] * (1.f / NN);
    float var = ws[INSQ_OFF + c] * (1.f / NN) - mu * mu;
    float sc  = g[c] * rsqrtf(var + BN_EPS);
    ws[SCALE_OFF + c] = sc;
    ws[SHIFT_OFF + c] = b[c] - mu * sc;
}

// fold input-BN scale into W1:  W1'[i][k][o] = scale[k]*W1[i][k][o]
__global__ void k_fold(const float* __restrict__ W1, float* __restrict__ ws) {
    int idx = blockIdx.x * blockDim.x + threadIdx.x;   // < 3*128*64
    int k = (idx >> 6) & (CIN - 1);
    ws[W1P_OFF + idx] = ws[SCALE_OFF + k] * W1[idx];
}

// c1[i][o] = sum_k shift[k]*W1[i][k][o]
__global__ void k_c1(const float* __restrict__ W1, float* __restrict__ ws) {
    int i = blockIdx.x, o = threadIdx.x;   // 3 blocks x 64
    float acc = 0.f;
    for (int k = 0; k < CIN; ++k)
        acc = fmaf(ws[SHIFT_OFF + k], W1[i * CIN * COUT + k * COUT + o], acc);
    ws[C1_OFF + i * COUT + o] = acc;
}

// ---- two-level bucket sort of edges by dst (blockIdx.y = branch) ----
__global__ __launch_bounds__(256) void k_sort_hist(const int* __restrict__ e0,
                                                   const int* __restrict__ e1,
                                                   const int* __restrict__ e2,
                                                   int* __restrict__ wsi) {
    int z = blockIdx.y;
    const int* ei = (z == 0) ? e0 : (z == 1) ? e1 : e2;
    __shared__ int h[NB];
    for (int i = threadIdx.x; i < NB; i += 256) h[i] = 0;
    __syncthreads();
    int beg = blockIdx.x * CHUNK_E;
    int end = min(NE, beg + CHUNK_E);
    for (int e = beg + threadIdx.x; e < end; e += 256)
        atomicAdd(&h[ei[NE + e] >> 8], 1);
    __syncthreads();
    int* off = wsi + OFF_OFF + z * (NB * NBLK1);
    for (int i = threadIdx.x; i < NB; i += 256)
        off[i * NBLK1 + blockIdx.x] = h[i];
}

__global__ __launch_bounds__(1024) void k_sort_scan(int* __restrict__ wsi) {
    int z = blockIdx.x;
    int* off = wsi + OFF_OFF + z * (NB * NBLK1);
    const int TOT = NB * NBLK1;              // 50048
    const int CH = (TOT + 1023) / 1024;      // 49
    __shared__ int sh[1024];
    int t = threadIdx.x;
    int base = t * CH;
    int s = 0;
    for (int i = 0; i < CH; ++i) {
        int idx = base + i;
        if (idx < TOT) s += off[idx];
    }
    sh[t] = s;
    __syncthreads();
    for (int o = 1; o < 1024; o <<= 1) {
        int v = (t >= o) ? sh[t - o] : 0;
        __syncthreads();
        sh[t] += v;
        __syncthreads();
    }
    int run = sh[t] - s;
    for (int i = 0; i < CH; ++i) {
        int idx = base + i;
        if (idx < TOT) {
            int v = off[idx];
            off[idx] = run;
            run += v;
        }
    }
}

// phase 3: scatter edges into bucket-contiguous temp, PACKED one word/edge:
// (dst&255)<<24 | src   (src < 2^17 fits in 24 bits)
__global__ __launch_bounds__(256) void k_sort_scatter(const int* __restrict__ e0,
                                                      const int* __restrict__ e1,
                                                      const int* __restrict__ e2,
                                                      int* __restrict__ wsi) {
    int z = blockIdx.y;
    const int* ei = (z == 0) ? e0 : (z == 1) ? e1 : e2;
    const int* off = wsi + OFF_OFF + z * (NB * NBLK1);
    unsigned* temp = (unsigned*)wsi + (size_t)z * NE;
    __shared__ int cur[NB];
    for (int i = threadIdx.x; i < NB; i += 256)
        cur[i] = off[i * NBLK1 + blockIdx.x];
    __syncthreads();
    int beg = blockIdx.x * CHUNK_E;
    int end = min(NE, beg + CHUNK_E);
    for (int e = beg + threadIdx.x; e < end; e += 256) {
        int d = ei[NE + e];
        int s = ei[e];
        int pos = atomicAdd(&cur[d >> 8], 1);
        temp[pos] = ((unsigned)(d & 255) << 24) | (unsigned)s;
    }
}

__global__ __launch_bounds__(256) void k_bucket(int* __restrict__ wsi) {
    int z = blockIdx.y, bk = blockIdx.x;
    const int* off = wsi + OFF_OFF + z * (NB * NBLK1);
    const unsigned* temp = (const unsigned*)wsi + (size_t)z * NE;
    int* col    = wsi + COL_OFF + z * NE;
    int* rowptr = wsi + ROWPTR_OFF + z * (NN + 1);
    int bs = off[bk * NBLK1];
    int be = (bk + 1 < NB) ? off[(bk + 1) * NBLK1] : NE;
    __shared__ int h[256], sc[256], cur[256];
    int t = threadIdx.x;
    h[t] = 0;
    __syncthreads();
    for (int e = bs + t; e < be; e += 256)
        atomicAdd(&h[temp[e] >> 24], 1);
    __syncthreads();
    int v = h[t];
    sc[t] = v;
    __syncthreads();
    for (int o = 1; o < 256; o <<= 1) {
        int u = (t >= o) ? sc[t - o] : 0;
        __syncthreads();
        sc[t] += u;
        __syncthreads();
    }
    int excl = sc[t] - v;
    int gd = bk * 256 + t;
    if (gd <= NN) rowptr[gd] = bs + excl;   // gd==NN lands on empty tail -> NE
    cur[t] = excl;
    __syncthreads();
    for (int e = bs + t; e < be; e += 256) {
        unsigned p = temp[e];
        int pos = atomicAdd(&cur[p >> 24], 1);
        col[bs + pos] = (int)(p & 0x00FFFFFFu);
    }
}

// y1b for ALL 3 branches in one pass (8 nodes/wave x 16-ch chunks x 3 br)
__global__ __launch_bounds__(256, 2) void k_gemm1(const float* __restrict__ x,
                                                  const float* __restrict__ W1p_all,
                                                  const float* __restrict__ c1_all,
                                                  unsigned* __restrict__ y1b_all) {
    int lane = threadIdx.x & 63;
    int wave = (blockIdx.x * blockDim.x + threadIdx.x) >> 6;
    int nw   = (gridDim.x * blockDim.x) >> 6;
    float c1v0 = c1_all[lane];
    float c1v1 = c1_all[COUT + lane];
    float c1v2 = c1_all[2 * COUT + lane];
    const int NGRP = NN / 8;   // 12500
    for (int g = wave; g < NGRP; g += nw) {
        int n0 = __builtin_amdgcn_readfirstlane(g) * 8;
        const float* __restrict__ xr = x + (size_t)n0 * CIN;
        float a0[8], a1[8], a2[8];
        #pragma unroll
        for (int i = 0; i < 8; ++i) { a0[i] = c1v0; a1[i] = c1v1; a2[i] = c1v2; }
        #pragma unroll 1
        for (int kc = 0; kc < CIN; kc += 16) {
            float w0[16], w1[16], w2[16];
            #pragma unroll
            for (int j = 0; j < 16; ++j) {
                w0[j] = W1p_all[(kc + j) * COUT + lane];
                w1[j] = W1p_all[CIN * COUT + (kc + j) * COUT + lane];
                w2[j] = W1p_all[2 * CIN * COUT + (kc + j) * COUT + lane];
            }
            #pragma unroll
            for (int i = 0; i < 8; ++i) {
                #pragma unroll
                for (int j = 0; j < 16; ++j) {
                    float xv = xr[i * CIN + kc + j];
                    a0[i] = fmaf(xv, w0[j], a0[i]);
                    a1[i] = fmaf(xv, w1[j], a1[i]);
                    a2[i] = fmaf(xv, w2[j], a2[i]);
                }
            }
        }
        #define STORE_NODE(zz, az, i) { \
            float vhi_ = __shfl(az[i], (lane & 31) + 32); \
            if (lane < 32) { \
                unsigned wrd_ = bf16_rne(az[i]) | (bf16_rne(vhi_) << 16); \
                y1b_all[((size_t)(zz) * NN + n0 + (i)) * 32 + lane] = wrd_; \
            } }
        #pragma unroll
        for (int i = 0; i < 8; ++i) {
            STORE_NODE(0, a0, i)
            STORE_NODE(1, a1, i)
            STORE_NODE(2, a2, i)
        }
        #undef STORE_NODE
    }
}

// aggregation + layer-1 epilogue, QUARTER-WAVE per node (16 lanes x uint2).
__global__ __launch_bounds__(256) void k_gather(const float* __restrict__ b1all,
                                                float* __restrict__ tall,
                                                float* __restrict__ ws) {
    int z = blockIdx.y;
    const uint2* __restrict__ y2 =
        (const uint2*)((const unsigned*)ws + Y1B_OFF + (size_t)z * NN * 32);
    float* __restrict__ t = tall + (size_t)z * NN * COUT;
    const int* __restrict__ rowptr = (const int*)ws + ROWPTR_OFF + z * (NN + 1);
    const int* __restrict__ col    = (const int*)ws + COL_OFF + z * NE;
    int lane = threadIdx.x & 63;
    int q = lane & 15;
    int quarter = lane >> 4;
    float b1a = b1all[z * COUT + 2 * q];
    float b1b = b1all[z * COUT + 2 * q + 1];
    float b1c = b1all[z * COUT + 32 + 2 * q];
    float b1d = b1all[z * COUT + 33 + 2 * q];
    int wave = (blockIdx.x * blockDim.x + threadIdx.x) >> 6;
    int nw   = (gridDim.x * blockDim.x) >> 6;
    const int NG = NN / 4;   // 25000 groups of 4 nodes
    for (int g = wave; g < NG; g += nw) {
        int n = g * 4 + quarter;
        int beg = rowptr[n], end = rowptr[n + 1];
        uint2 su = y2[(size_t)n * 16 + q];
        float aa = lo16f(su.x), ab = hi16f(su.x);
        float ac = lo16f(su.y), ad = hi16f(su.y);
        float ba = 0.f, bb = 0.f, bc = 0.f, bd = 0.f;
        float ca = 0.f, cb = 0.f, cc = 0.f, cd = 0.f;
        float da = 0.f, db = 0.f, dc = 0.f, dd = 0.f;
        int j = beg;
        for (; j + 3 < end; j += 4) {
            int c0 = col[j], c1 = col[j + 1], c2 = col[j + 2], c3 = col[j + 3];
            uint2 u0 = y2[(size_t)c0 * 16 + q];
            uint2 u1 = y2[(size_t)c1 * 16 + q];
            uint2 u2 = y2[(size_t)c2 * 16 + q];
            uint2 u3 = y2[(size_t)c3 * 16 + q];
            aa += lo16f(u0.x); ab += hi16f(u0.x); ac += lo16f(u0.y); ad += hi16f(u0.y);
            ba += lo16f(u1.x); bb += hi16f(u1.x); bc += lo16f(u1.y); bd += hi16f(u1.y);
            ca += lo16f(u2.x); cb += hi16f(u2.x); cc += lo16f(u2.y); cd += hi16f(u2.y);
            da += lo16f(u3.x); db += hi16f(u3.x); dc += lo16f(u3.y); dd += hi16f(u3.y);
        }
        for (; j < end; ++j) {
            uint2 u = y2[(size_t)col[j] * 16 + q];
            aa += lo16f(u.x); ab += hi16f(u.x); ac += lo16f(u.y); ad += hi16f(u.y);
        }
        float2 lo = make_float2(fmaxf((aa + ba) + (ca + da) + b1a, 0.f),
                                fmaxf((ac + bc) + (cc + dc) + b1b, 0.f));
        float2 hi = make_float2(fmaxf((ab + bb) + (cb + db) + b1c, 0.f),
                                fmaxf((ad + bd) + (cd + dd) + b1d, 0.f));
        *(float2*)(t + (size_t)n * 64 + 2 * q)      = lo;
        *(float2*)(t + (size_t)n * 64 + 32 + 2 * q) = hi;
    }
}

// MLP2 v5, in-place on d_out: wave-group = 64 nodes, lane = node.
// t rows: coalesced stage into padded per-wave LDS tile -> 16 per-lane
// ds_read_b128 pull the lane's whole row into 16 float4 REGISTERS.
// W2[j][o]: wave-uniform s_load -> SGPR FMA operand (64 FMAs per dwordx16,
// hidden under the 4096-FMA stream). No barriers (wave-private LDS).
// h2 written back via LDS (coalesced). BN stats in separate pass.
__global__ __launch_bounds__(128) void k_mlp2(const float* __restrict__ W2all,
                                              const float* __restrict__ b2all,
                                              float* __restrict__ outall) {
    int z = blockIdx.y;
    __shared__ float ts[2][MT][68];      // 34.8 KB, one tile per wave
    const float* __restrict__ W2 = W2all + z * COUT * COUT;
    const float* __restrict__ b2 = b2all + z * COUT;
    float* __restrict__ out = outall + (size_t)z * NN * COUT;
    int lane = threadIdx.x & 63;
    int wv = threadIdx.x >> 6;           // 0..1
    int grp = blockIdx.x * 2 + wv;
    if (grp >= MG) return;
    float (*T)[68] = ts[wv];
    // ---- stage 64x64 t tile, coalesced global -> padded LDS
    #pragma unroll
    for (int it = 0; it < 16; ++it) {
        int f = it * 64 + lane;          // float4 index 0..1023
        int nd = f >> 4, jq = f & 15;
        int ng = grp * MT + nd;
        if (ng > NN - 1) ng = NN - 1;
        float4 v = *(const float4*)(out + (size_t)ng * COUT + jq * 4);
        *(float4*)&T[nd][jq * 4] = v;
    }
    // ---- pull own row into registers (per-lane b128, 8-way conflict max)
    float4 T0 = *(float4*)&T[lane][0],  T1 = *(float4*)&T[lane][4];
    float4 T2 = *(float4*)&T[lane][8],  T3 = *(float4*)&T[lane][12];
    float4 T4 = *(float4*)&T[lane][16], T5 = *(float4*)&T[lane][20];
    float4 T6 = *(float4*)&T[lane][24], T7 = *(float4*)&T[lane][28];
    float4 T8 = *(float4*)&T[lane][32], T9 = *(float4*)&T[lane][36];
    float4 T10 = *(float4*)&T[lane][40], T11 = *(float4*)&T[lane][44];
    float4 T12 = *(float4*)&T[lane][48], T13 = *(float4*)&T[lane][52];
    float4 T14 = *(float4*)&T[lane][56], T15 = *(float4*)&T[lane][60];
    // ---- compute 16 outputs per pass; W2 via uniform scalar loads
    #pragma unroll 1
    for (int p = 0; p < 4; ++p) {
        const float* __restrict__ w2p = W2 + p * 16;
        float acc[16];
        #pragma unroll
        for (int o = 0; o < 16; ++o) acc[o] = b2[p * 16 + o];
#define FMA16(tv, jj) { float tv_ = (tv); \
        _Pragma("unroll") \
        for (int o = 0; o < 16; ++o) \
            acc[o] = fmaf(tv_, w2p[(jj) * COUT + o], acc[o]); }
#define DO4(Tv, jb) FMA16(Tv.x, 4*(jb)) FMA16(Tv.y, 4*(jb)+1) \
                    FMA16(Tv.z, 4*(jb)+2) FMA16(Tv.w, 4*(jb)+3)
        DO4(T0, 0)  DO4(T1, 1)  DO4(T2, 2)  DO4(T3, 3)
        DO4(T4, 4)  DO4(T5, 5)  DO4(T6, 6)  DO4(T7, 7)
        DO4(T8, 8)  DO4(T9, 9)  DO4(T10, 10) DO4(T11, 11)
        DO4(T12, 12) DO4(T13, 13) DO4(T14, 14) DO4(T15, 15)
#undef DO4
#undef FMA16
        *(float4*)&T[lane][p * 16 + 0]  = make_float4(acc[0], acc[1], acc[2], acc[3]);
        *(float4*)&T[lane][p * 16 + 4]  = make_float4(acc[4], acc[5], acc[6], acc[7]);
        *(float4*)&T[lane][p * 16 + 8]  = make_float4(acc[8], acc[9], acc[10], acc[11]);
        *(float4*)&T[lane][p * 16 + 12] = make_float4(acc[12], acc[13], acc[14], acc[15]);
    }
    // ---- coalesced write-back
    #pragma unroll
    for (int it = 0; it < 16; ++it) {
        int f = it * 64 + lane;
        int nd = f >> 4, jq = f & 15;
        int ng = grp * MT + nd;
        if (ng < NN)
            *(float4*)(out + (size_t)ng * COUT + jq * 4) = *(float4*)&T[nd][jq * 4];
    }
}

// BN stats over h2 (coalesced pass; lane = channel)
__global__ __launch_bounds__(256) void k_h2_stats(const float* __restrict__ outall,
                                                  float* __restrict__ ws) {
    int z = blockIdx.y;
    const float* __restrict__ h = outall + (size_t)z * NN * COUT;
    int tid = blockIdx.x * blockDim.x + threadIdx.x;
    int o = tid & 63;
    int r0 = tid >> 6;
    int rs = (gridDim.x * blockDim.x) >> 6;
    float s = 0.f, ss = 0.f;
    for (int r = r0; r < NN; r += rs) {
        float v = h[(size_t)r * COUT + o];
        s += v; ss += v * v;
    }
    unsafeAtomicAdd(&ws[OSUM_OFF + z * COUT + o], s);
    unsafeAtomicAdd(&ws[OSQ_OFF + z * COUT + o], ss);
}

__global__ void k_obn_final(const float* __restrict__ g, const float* __restrict__ b,
                            float* __restrict__ ws) {
    int br = blockIdx.x;   // 3 blocks x 64
    int o = threadIdx.x;
    float mu  = ws[OSUM_OFF + br * COUT + o] * (1.f / NN);
    float var = ws[OSQ_OFF  + br * COUT + o] * (1.f / NN) - mu * mu;
    float sc  = g[br * COUT + o] * rsqrtf(var + BN_EPS);
    ws[OBNS_OFF + br * COUT + o] = sc;
    ws[OBNB_OFF + br * COUT + o] = b[br * COUT + o] - mu * sc;
}

// y = tanh(sc[c]*h2 + sh[c]) in-place; blockIdx.y = branch
__global__ __launch_bounds__(256) void k_apply(float* __restrict__ outall,
                                               const float* __restrict__ ws) {
    int z = blockIdx.y;
    float* out = outall + (size_t)z * NN * COUT;
    const float* __restrict__ sc = ws + OBNS_OFF + z * COUT;
    const float* __restrict__ sh = ws + OBNB_OFF + z * COUT;
    int idx = blockIdx.x * blockDim.x + threadIdx.x;
    int stride = gridDim.x * blockDim.x;
    const int total = NN * COUT / 4;
    float4* o4 = (float4*)out;
    for (int v = idx; v < total; v += stride) {
        int c = (v & 15) * 4;
        float4 f = o4[v];
        f.x = tanhf(fmaf(f.x, sc[c],     sh[c]));
        f.y = tanhf(fmaf(f.y, sc[c + 1], sh[c + 1]));
        f.z = tanhf(fmaf(f.z, sc[c + 2], sh[c + 2]));
        f.w = tanhf(fmaf(f.w, sc[c + 3], sh[c + 3]));
        o4[v] = f;
    }
}

extern "C" void kernel_launch(void* const* d_in, const int* in_sizes, int n_in,
                              void* d_out, int out_size, void* d_ws, size_t ws_size,
                              hipStream_t stream) {
    const float* x   = (const float*)d_in[0];
    const int*   eip = (const int*)d_in[1];
    const int*   eis = (const int*)d_in[2];
    const int*   eiv = (const int*)d_in[3];
    const float* ig  = (const float*)d_in[4];
    const float* ib  = (const float*)d_in[5];
    const float* W1  = (const float*)d_in[6];
    const float* b1  = (const float*)d_in[7];
    const float* W2  = (const float*)d_in[8];
    const float* b2  = (const float*)d_in[9];
    const float* bng = (const float*)d_in[10];
    const float* bnb = (const float*)d_in[11];
    float* out = (float*)d_out;
    float* ws  = (float*)d_ws;
    int*   wsi = (int*)d_ws;

    hipMemsetAsync(ws + ZERO_OFF, 0, ZERO_CNT * sizeof(float), stream);

    k_in_stats<<<256, 256, 0, stream>>>(x, ws);
    k_in_finalize<<<1, 128, 0, stream>>>(ig, ib, ws);
    k_fold<<<96, 256, 0, stream>>>(W1, ws);
    k_c1<<<3, 64, 0, stream>>>(W1, ws);

    // two-level bucket sort -> CSR for all 3 branches (temp overlaps y1b3;
    // all sort kernels complete before k_gemm1)
    k_sort_hist<<<dim3(NBLK1, 3), 256, 0, stream>>>(eip, eis, eiv, wsi);
    k_sort_scan<<<3, 1024, 0, stream>>>(wsi);
    k_sort_scatter<<<dim3(NBLK1, 3), 256, 0, stream>>>(eip, eis, eiv, wsi);
    k_bucket<<<dim3(NB, 3), 256, 0, stream>>>(wsi);

    // gemm1: single pass over x computes all 3 branches
    k_gemm1<<<1024, 256, 0, stream>>>(x, ws + W1P_OFF, ws + C1_OFF,
                                      (unsigned*)ws + Y1B_OFF);
    k_gather<<<dim3(2048, 3), 256, 0, stream>>>(b1, out, ws);
    k_mlp2<<<dim3((MG + 1) / 2, 3), 128, 0, stream>>>(W2, b2, out);
    k_h2_stats<<<dim3(256, 3), 256, 0, stream>>>(out, ws);
    k_obn_final<<<3, 64, 0, stream>>>(bng, bnb, ws);
    k_apply<<<dim3(1024, 3), 256, 0, stream>>>(out, ws);
}